// Round 5
// baseline (864.382 us; speedup 1.0000x reference)
//
#include <hip/hip_runtime.h>

#define V 49152
#define B 4
#define T 8
#define NNZ (9 * V)
#define EPS 1e-5f
#define SLOTS 32

typedef __attribute__((ext_vector_type(8))) short bf16x8;
typedef __attribute__((ext_vector_type(4))) float f32x4;
typedef __attribute__((ext_vector_type(4))) float float4v;
typedef __attribute__((ext_vector_type(8))) unsigned short u16x8;
typedef __attribute__((ext_vector_type(4))) unsigned short u16x4;

// ---------------- ws layout (bytes) ----------------
#define STATS_OFF 0LL          // 256 floats: sum[64]|sumsq[64]|scale[64]|shift[64]
#define CNT_OFF   1024LL       // V ints
#define CSRC_OFF  197632LL     // V*SLOTS ints
#define CSRV_OFF  6489088LL    // V*SLOTS floats
#define X0B_OFF   12780544LL   // V*1024 bf16   (memset zeroes [0, X0B_OFF))
#define X1B_OFF   113443840LL  // V*1024 bf16
#define YB_OFF    214107136LL  // B*V*T*64 bf16 (only if ws is big enough)
#define WS_NEED_YB 415433728LL

__device__ inline unsigned short f2bf(float f) {
    unsigned u = __builtin_bit_cast(unsigned, f);
    u += 0x7fffu + ((u >> 16) & 1u);
    return (unsigned short)(u >> 16);
}
__device__ inline float bf2f(unsigned short h) {
    return __builtin_bit_cast(float, ((unsigned)h) << 16);
}
__device__ inline void wave_lds_sync() {
    asm volatile("s_waitcnt lgkmcnt(0)" ::: "memory");
}
// 16B-slot XOR swizzle within a 2KB (1024-short) region: kills the 8-lane
// 2-bank pileup of the x2 A-fragment reads (t-stride 64B -> bank stride 16).
__device__ inline int swz2k(int soff) {      // soff in shorts, multiple of 8
    int slot = soff >> 3;
    return (slot ^ ((slot >> 3) & 7)) << 3;
}

// ---------------- convert x fp32 [B][V][T*F] -> bf16 [V][B][T*F] ----------------
__global__ __launch_bounds__(256)
void convert_kernel(const float* __restrict__ x, unsigned short* __restrict__ x0b) {
    unsigned gid = blockIdx.x * 256 + threadIdx.x;
    unsigned idx = gid * 8;
    unsigned j = idx & 255;
    unsigned bv = idx >> 8;
    unsigned b = bv / V;
    unsigned v = bv - b * V;
    const float4v* src = (const float4v*)(x + idx);
    float4v f0 = src[0], f1 = src[1];
    u16x8 o;
    o[0] = f2bf(f0[0]); o[1] = f2bf(f0[1]); o[2] = f2bf(f0[2]); o[3] = f2bf(f0[3]);
    o[4] = f2bf(f1[0]); o[5] = f2bf(f1[1]); o[6] = f2bf(f1[2]); o[7] = f2bf(f1[3]);
    *(u16x8*)(x0b + v * 1024 + b * 256 + j) = o;
}

// ---------------- padded-CSR build (pad slots stay 0 from memset) ----------------
__global__ __launch_bounds__(256)
void scatter_kernel(const int* __restrict__ rows, const int* __restrict__ cols,
                    const float* __restrict__ vals, int* __restrict__ cnt,
                    int* __restrict__ csr_c, float* __restrict__ csr_v) {
    int e = blockIdx.x * 256 + threadIdx.x;
    if (e >= NNZ) return;
    int r = rows[e];
    int slot = atomicAdd(&cnt[r], 1);
    if (slot < SLOTS) {
        csr_c[r * SLOTS + slot] = cols[e];
        csr_v[r * SLOTS + slot] = vals[e];
    }
}

// ---------------- SpMM 1: x1 = L @ x0; 2 rows/block, 128 thr/row, fixed-16 unroll ----------------
__global__ __launch_bounds__(256)
void spmm1_kernel(const unsigned short* __restrict__ x0b, const int* __restrict__ cnt,
                  const int* __restrict__ csr_c, const float* __restrict__ csr_v,
                  unsigned short* __restrict__ x1b) {
    int r = blockIdx.x * 2 + (threadIdx.x >> 7);
    int j = (threadIdx.x & 127) * 8;
    int n = min(cnt[r], SLOTS);
    const int* cc = csr_c + r * SLOTS;
    const float* cv = csr_v + r * SLOTS;
    float s[8];
    #pragma unroll
    for (int i = 0; i < 8; ++i) s[i] = 0.f;
    #pragma unroll
    for (int e = 0; e < 16; ++e) {     // pads: c=0, val=0 -> L1-broadcast, contributes 0
        int c = cc[e];
        float val = cv[e];
        u16x8 xv = *(const u16x8*)(x0b + c * 1024 + j);
        #pragma unroll
        for (int i = 0; i < 8; ++i) s[i] = fmaf(val, bf2f(xv[i]), s[i]);
    }
    if (n > 16) {
        for (int e = 16; e < n; ++e) {
            int c = cc[e];
            float val = cv[e];
            u16x8 xv = *(const u16x8*)(x0b + c * 1024 + j);
            #pragma unroll
            for (int i = 0; i < 8; ++i) s[i] = fmaf(val, bf2f(xv[i]), s[i]);
        }
    }
    u16x8 o;
    #pragma unroll
    for (int i = 0; i < 8; ++i) o[i] = f2bf(s[i]);
    *(u16x8*)(x1b + r * 1024 + j) = o;
}

// ---------------- fused: spmm2 (x2 per v, wave-private swizzled LDS) + MFMA + BN stats ----------------
template<int YBF>
__global__ __launch_bounds__(256, 3)
void dense_kernel(const unsigned short* __restrict__ x0b, const unsigned short* __restrict__ x1b,
                  const int* __restrict__ cnt, const int* __restrict__ csr_c,
                  const float* __restrict__ csr_v, const float* __restrict__ W,
                  float* __restrict__ stats, unsigned short* __restrict__ yb,
                  float* __restrict__ yf) {
    __shared__ short wt[64 * 296];     // W^T: wt[o][k]; dword-stride 148 (odd/2) -> <=2-way = free
    __shared__ short x2l[4][1024];     // per-wave x2[v] slice, XOR-swizzled 16B slots
    __shared__ float sstat[128];

    for (int idx = threadIdx.x; idx < 288 * 64; idx += 256) {
        int k = idx >> 6, o = idx & 63;
        wt[o * 296 + k] = (short)f2bf(W[idx]);
    }
    if (threadIdx.x < 128) sstat[threadIdx.x] = 0.f;
    __syncthreads();   // the only block barrier

    const int wave = threadIdx.x >> 6;
    const int lane = threadIdx.x & 63;
    const int l15 = lane & 15, lhi = lane >> 4;
    const int f0 = lhi * 8;
    const int jb = lane * 16;

    float ssum[4] = {0.f, 0.f, 0.f, 0.f};
    float ssq[4]  = {0.f, 0.f, 0.f, 0.f};

    for (int vi = 0; vi < 16; ++vi) {
        const int v = blockIdx.x * 64 + vi * 4 + wave;

        // ---- issue x0/x1 A-fragment loads early (independent of the gather) ----
        bf16x8 afrag[2][9];
        #pragma unroll
        for (int mt = 0; mt < 2; ++mt) {
            const int m = mt * 16 + l15;
            const int b = m >> 3, t = m & 7;
            #pragma unroll
            for (int kc = 0; kc < 6; ++kc) {
                const int kk = kc / 3, tw = kc % 3;
                const int tp = t + tw - 1;
                bf16x8 a = {0, 0, 0, 0, 0, 0, 0, 0};
                if ((unsigned)tp < 8u) {
                    const unsigned short* src = (kk == 0) ? x0b : x1b;
                    a = *(const bf16x8*)(src + v * 1024 + b * 256 + tp * 32 + f0);
                }
                afrag[mt][kc] = a;
            }
        }

        // ---- phase A: x2[v] = 2*(L@x1)[v] - x0[v]; fixed-16 unrolled gathers ----
        {
            const int n = min(cnt[v], SLOTS);
            const int* cc = csr_c + v * SLOTS;
            const float* cv = csr_v + v * SLOTS;
            float s[16];
            #pragma unroll
            for (int i = 0; i < 16; ++i) s[i] = 0.f;
            #pragma unroll
            for (int e = 0; e < 16; ++e) {
                const int c = cc[e];
                const float val = cv[e];
                u16x8 a0 = *(const u16x8*)(x1b + c * 1024 + jb);
                u16x8 a1 = *(const u16x8*)(x1b + c * 1024 + jb + 8);
                #pragma unroll
                for (int i = 0; i < 8; ++i) {
                    s[i]     = fmaf(val, bf2f(a0[i]), s[i]);
                    s[8 + i] = fmaf(val, bf2f(a1[i]), s[8 + i]);
                }
            }
            if (n > 16) {
                for (int e = 16; e < n; ++e) {
                    const int c = cc[e];
                    const float val = cv[e];
                    u16x8 a0 = *(const u16x8*)(x1b + c * 1024 + jb);
                    u16x8 a1 = *(const u16x8*)(x1b + c * 1024 + jb + 8);
                    #pragma unroll
                    for (int i = 0; i < 8; ++i) {
                        s[i]     = fmaf(val, bf2f(a0[i]), s[i]);
                        s[8 + i] = fmaf(val, bf2f(a1[i]), s[8 + i]);
                    }
                }
            }
            u16x8 z0 = *(const u16x8*)(x0b + v * 1024 + jb);
            u16x8 z1 = *(const u16x8*)(x0b + v * 1024 + jb + 8);
            u16x8 o0, o1;
            #pragma unroll
            for (int i = 0; i < 8; ++i) {
                o0[i] = f2bf(2.f * s[i] - bf2f(z0[i]));
                o1[i] = f2bf(2.f * s[8 + i] - bf2f(z1[i]));
            }
            *(u16x8*)&x2l[wave][swz2k(jb)] = o0;
            *(u16x8*)&x2l[wave][swz2k(jb + 8)] = o1;
        }
        wave_lds_sync();   // wave's own ds_writes complete; DS in-order per wave

        // ---- x2 A-fragments from wave-private swizzled LDS ----
        #pragma unroll
        for (int mt = 0; mt < 2; ++mt) {
            const int m = mt * 16 + l15;
            const int b = m >> 3, t = m & 7;
            #pragma unroll
            for (int kc = 6; kc < 9; ++kc) {
                const int tw = kc % 3;
                const int tp = t + tw - 1;
                bf16x8 a = {0, 0, 0, 0, 0, 0, 0, 0};
                if ((unsigned)tp < 8u)
                    a = *(const bf16x8*)&x2l[wave][swz2k(b * 256 + tp * 32 + f0)];
                afrag[mt][kc] = a;
            }
        }

        // ---- phase B: MFMA ----
        f32x4 acc[2][4];
        #pragma unroll
        for (int mt = 0; mt < 2; ++mt)
            #pragma unroll
            for (int nt = 0; nt < 4; ++nt)
                acc[mt][nt] = (f32x4){0.f, 0.f, 0.f, 0.f};

        #pragma unroll
        for (int kc = 0; kc < 9; ++kc) {
            #pragma unroll
            for (int nt = 0; nt < 4; ++nt) {
                const int nrow = nt * 16 + l15;
                bf16x8 bfrag = *(const bf16x8*)&wt[nrow * 296 + kc * 32 + f0];
                #pragma unroll
                for (int mt = 0; mt < 2; ++mt)
                    acc[mt][nt] = __builtin_amdgcn_mfma_f32_16x16x32_bf16(
                        afrag[mt][kc], bfrag, acc[mt][nt], 0, 0, 0);
            }
        }

        // ---- epilogue: y store + stats partials (bias cancels under BN) ----
        #pragma unroll
        for (int mt = 0; mt < 2; ++mt)
            #pragma unroll
            for (int nt = 0; nt < 4; ++nt)
                #pragma unroll
                for (int i = 0; i < 4; ++i) {
                    const int m = mt * 16 + lhi * 4 + i;
                    const int b = m >> 3, t = m & 7;
                    const int col = nt * 16 + l15;
                    const float val = acc[mt][nt][i];
                    ssum[nt] += val;
                    ssq[nt]  += val * val;
                    const int idx = ((b * V + v) * 8 + t) * 64 + col;
                    if (YBF) yb[idx] = f2bf(val);
                    else     yf[idx] = val;
                }
    }

    #pragma unroll
    for (int nt = 0; nt < 4; ++nt) {
        const int col = nt * 16 + l15;
        atomicAdd(&sstat[col], ssum[nt]);
        atomicAdd(&sstat[64 + col], ssq[nt]);
    }
    __syncthreads();
    if (threadIdx.x < 128) atomicAdd(&stats[threadIdx.x], sstat[threadIdx.x]);
}

// ---------------- fold mean/var/gamma/beta -> scale/shift ----------------
__global__ __launch_bounds__(64)
void finalize_kernel(const float* __restrict__ gamma, const float* __restrict__ beta,
                     float* __restrict__ stats) {
    int o = threadIdx.x;
    float n = (float)(B * V * T);
    float mean = stats[o] / n;
    float var = stats[64 + o] / n - mean * mean;
    float sc = gamma[o] * rsqrtf(var + EPS);
    stats[128 + o] = sc;
    stats[192 + o] = beta[o] - mean * sc;
}

// ---------------- normalize + ReLU ----------------
template<int YBF>
__global__ __launch_bounds__(256)
void norm_kernel(const unsigned short* __restrict__ yb, float* __restrict__ out,
                 const float* __restrict__ stats) {
    const int total = B * V * T * 64;
    if (YBF) {
        const int start = (blockIdx.x * 256 + threadIdx.x) * 8;
        const int ob = start & 63;
        float sc[8], sh[8];
        #pragma unroll
        for (int c = 0; c < 8; ++c) { sc[c] = stats[128 + ob + c]; sh[c] = stats[192 + ob + c]; }
        for (int i0 = start; i0 < total; i0 += gridDim.x * 256 * 8) {
            u16x8 yv = *(const u16x8*)(yb + i0);
            float4v r0, r1;
            #pragma unroll
            for (int c = 0; c < 8; ++c) {
                float val = fmaxf(bf2f(yv[c]) * sc[c] + sh[c], 0.f);
                if (c < 4) r0[c] = val; else r1[c - 4] = val;
            }
            *(float4v*)(out + i0) = r0;
            *(float4v*)(out + i0 + 4) = r1;
        }
    } else {
        const int start = (blockIdx.x * 256 + threadIdx.x) * 4;
        const int ob = start & 63;
        float sc[4], sh[4];
        #pragma unroll
        for (int c = 0; c < 4; ++c) { sc[c] = stats[128 + ob + c]; sh[c] = stats[192 + ob + c]; }
        for (int i0 = start; i0 < total; i0 += gridDim.x * 256 * 4) {
            float4v v4 = *(float4v*)(out + i0);
            #pragma unroll
            for (int c = 0; c < 4; ++c)
                v4[c] = fmaxf(v4[c] * sc[c] + sh[c], 0.f);
            *(float4v*)(out + i0) = v4;
        }
    }
}

extern "C" void kernel_launch(void* const* d_in, const int* in_sizes, int n_in,
                              void* d_out, int out_size, void* d_ws, size_t ws_size,
                              hipStream_t stream) {
    const float* x        = (const float*)d_in[0];
    const float* lap_vals = (const float*)d_in[1];
    const float* W        = (const float*)d_in[2];
    // d_in[3] = bias: cancels exactly under training-mode BN
    const float* gamma    = (const float*)d_in[4];
    const float* beta     = (const float*)d_in[5];
    const int*   rows     = (const int*)d_in[6];
    const int*   cols     = (const int*)d_in[7];
    float* out = (float*)d_out;
    char*  ws  = (char*)d_ws;

    float*          stats = (float*)(ws + STATS_OFF);
    int*            cnt   = (int*)(ws + CNT_OFF);
    int*            csr_c = (int*)(ws + CSRC_OFF);
    float*          csr_v = (float*)(ws + CSRV_OFF);
    unsigned short* x0b   = (unsigned short*)(ws + X0B_OFF);
    unsigned short* x1b   = (unsigned short*)(ws + X1B_OFF);
    unsigned short* ybp   = (unsigned short*)(ws + YB_OFF);

    const bool ybf = (ws_size >= (size_t)WS_NEED_YB);

    // zero stats + cnt + csr arrays (csr zero-fill makes padded slots inert)
    hipMemsetAsync(ws + STATS_OFF, 0, (size_t)X0B_OFF, stream);

    convert_kernel<<<24576, 256, 0, stream>>>(x, x0b);
    scatter_kernel<<<(NNZ + 255) / 256, 256, 0, stream>>>(rows, cols, lap_vals, cnt, csr_c, csr_v);
    spmm1_kernel<<<V / 2, 256, 0, stream>>>(x0b, cnt, csr_c, csr_v, x1b);
    if (ybf) dense_kernel<1><<<V / 64, 256, 0, stream>>>(x0b, x1b, cnt, csr_c, csr_v, W, stats, ybp, nullptr);
    else     dense_kernel<0><<<V / 64, 256, 0, stream>>>(x0b, x1b, cnt, csr_c, csr_v, W, stats, nullptr, out);
    finalize_kernel<<<1, 64, 0, stream>>>(gamma, beta, stats);
    if (ybf) norm_kernel<1><<<4096, 256, 0, stream>>>(ybp, out, stats);
    else     norm_kernel<0><<<4096, 256, 0, stream>>>(nullptr, out, stats);
}

// Round 7
// 581.930 us; speedup vs baseline: 1.4854x; 1.4854x over previous
//
#include <hip/hip_runtime.h>

#define V 49152
#define B 4
#define T 8
#define NNZ (9 * V)
#define EPS 1e-5f
#define SLOTS 32

typedef __attribute__((ext_vector_type(8))) short bf16x8;
typedef __attribute__((ext_vector_type(4))) float f32x4;
typedef __attribute__((ext_vector_type(4))) float float4v;
typedef __attribute__((ext_vector_type(8))) unsigned short u16x8;
typedef __attribute__((ext_vector_type(4))) unsigned short u16x4;

// ---------------- ws layout (bytes) ----------------
#define STATS_OFF 0LL          // 256 floats: sum[64]|sumsq[64]|scale[64]|shift[64]
#define CNT_OFF   1024LL       // V ints
#define CSRC_OFF  197632LL     // V*SLOTS ints
#define CSRV_OFF  6489088LL    // V*SLOTS floats
#define X0B_OFF   12780544LL   // V*1024 bf16   (memset zeroes [0, X0B_OFF))
#define X1B_OFF   113443840LL  // V*1024 bf16
#define YB_OFF    214107136LL  // B*V*T*64 bf16 (only if ws is big enough)
#define WS_NEED_YB 415433728LL

__device__ inline unsigned short f2bf(float f) {
    unsigned u = __builtin_bit_cast(unsigned, f);
    u += 0x7fffu + ((u >> 16) & 1u);
    return (unsigned short)(u >> 16);
}
__device__ inline float bf2f(unsigned short h) {
    return __builtin_bit_cast(float, ((unsigned)h) << 16);
}

// ---------------- convert x fp32 [B][V][T*F] -> bf16 [V][B][T*F] ----------------
__global__ __launch_bounds__(256)
void convert_kernel(const float* __restrict__ x, unsigned short* __restrict__ x0b) {
    unsigned gid = blockIdx.x * 256 + threadIdx.x;   // V*128 threads total
    unsigned v = gid >> 7;
    unsigned s = gid & 127;              // 8-short chunk within the 1024-short row
    unsigned b = s >> 5;                 // s*8 / 256
    unsigned j = (s * 8) & 255;
    const float4v* src = (const float4v*)(x + (size_t)(b * V + v) * 256 + j);
    float4v f0 = src[0], f1 = src[1];
    u16x8 o;
    o[0] = f2bf(f0[0]); o[1] = f2bf(f0[1]); o[2] = f2bf(f0[2]); o[3] = f2bf(f0[3]);
    o[4] = f2bf(f1[0]); o[5] = f2bf(f1[1]); o[6] = f2bf(f1[2]); o[7] = f2bf(f1[3]);
    *(u16x8*)(x0b + v * 1024 + s * 8) = o;
}

// ---------------- padded-CSR build (pad slots stay 0 from memset) ----------------
__global__ __launch_bounds__(256)
void scatter_kernel(const int* __restrict__ rows, const int* __restrict__ cols,
                    const float* __restrict__ vals, int* __restrict__ cnt,
                    int* __restrict__ csr_c, float* __restrict__ csr_v) {
    int e = blockIdx.x * 256 + threadIdx.x;
    if (e >= NNZ) return;
    int r = rows[e];
    int slot = atomicAdd(&cnt[r], 1);
    if (slot < SLOTS) {
        csr_c[r * SLOTS + slot] = cols[e];
        csr_v[r * SLOTS + slot] = vals[e];
    }
}

// ---------------- SpMM 1: x1 = L @ x0 (chunk-8 unrolled gathers) ----------------
__global__ __launch_bounds__(256)
void spmm1_kernel(const unsigned short* __restrict__ x0b, const int* __restrict__ cnt,
                  const int* __restrict__ csr_c, const float* __restrict__ csr_v,
                  unsigned short* __restrict__ x1b) {
    int r = blockIdx.x;
    int j = threadIdx.x * 4;
    int n8 = (min(cnt[r], SLOTS) + 7) & ~7;
    const int* cc = csr_c + r * SLOTS;
    const float* cv = csr_v + r * SLOTS;
    float s0 = 0.f, s1 = 0.f, s2 = 0.f, s3 = 0.f;
    for (int e0 = 0; e0 < n8; e0 += 8) {
        #pragma unroll
        for (int u = 0; u < 8; ++u) {
            int c = cc[e0 + u];          // pad: c=0, val=0 -> contributes nothing
            float val = cv[e0 + u];
            u16x4 xv = *(const u16x4*)(x0b + c * 1024 + j);
            s0 = fmaf(val, bf2f(xv[0]), s0);
            s1 = fmaf(val, bf2f(xv[1]), s1);
            s2 = fmaf(val, bf2f(xv[2]), s2);
            s3 = fmaf(val, bf2f(xv[3]), s3);
        }
    }
    u16x4 o;
    o[0] = f2bf(s0); o[1] = f2bf(s1); o[2] = f2bf(s2); o[3] = f2bf(s3);
    *(u16x4*)(x1b + r * 1024 + j) = o;
}

// ---------------- fused: spmm2 (x2 per v, wave-private LDS) + dense MFMA + BN stats ----------------
// 64 v per block, 4 waves. RAW on x2l fenced by a plain __syncthreads per vi
// (the inline-asm wave-local fence was the prime suspect for a flaky post-timing
// divergence). WAR across vi iterations is safe: DS ops issue in order per wave.
template<int YBF>
__global__ __launch_bounds__(256, 3)
void dense_kernel(const unsigned short* __restrict__ x0b, const unsigned short* __restrict__ x1b,
                  const int* __restrict__ cnt, const int* __restrict__ csr_c,
                  const float* __restrict__ csr_v, const float* __restrict__ W,
                  float* __restrict__ stats, unsigned short* __restrict__ yb,
                  float* __restrict__ yf) {
    __shared__ short wt[64 * 296];     // W^T: wt[o][k]; dword-stride 148 -> <=2-way = free
    __shared__ short x2l[4][1024];     // per-wave x2[v] slice (wave-private)
    __shared__ float sstat[128];

    for (int idx = threadIdx.x; idx < 288 * 64; idx += 256) {
        int k = idx >> 6, o = idx & 63;
        wt[o * 296 + k] = (short)f2bf(W[idx]);
    }
    if (threadIdx.x < 128) sstat[threadIdx.x] = 0.f;
    __syncthreads();

    const int wave = threadIdx.x >> 6;
    const int lane = threadIdx.x & 63;
    const int l15 = lane & 15, lhi = lane >> 4;
    const int f0 = lhi * 8;
    const int jb = lane * 16;

    float ssum[4] = {0.f, 0.f, 0.f, 0.f};
    float ssq[4]  = {0.f, 0.f, 0.f, 0.f};

    for (int vi = 0; vi < 16; ++vi) {
        const int v = blockIdx.x * 64 + vi * 4 + wave;

        // ---- issue x0/x1 A-fragment loads early (independent of the gather) ----
        bf16x8 afrag[2][9];
        #pragma unroll
        for (int mt = 0; mt < 2; ++mt) {
            const int m = mt * 16 + l15;
            const int b = m >> 3, t = m & 7;
            #pragma unroll
            for (int kc = 0; kc < 6; ++kc) {
                const int kk = kc / 3, tw = kc % 3;
                const int tp = t + tw - 1;
                bf16x8 a = {0, 0, 0, 0, 0, 0, 0, 0};
                if ((unsigned)tp < 8u) {
                    const unsigned short* src = (kk == 0) ? x0b : x1b;
                    a = *(const bf16x8*)(src + v * 1024 + b * 256 + tp * 32 + f0);
                }
                afrag[mt][kc] = a;
            }
        }

        // ---- phase A: x2[v] = 2*(L@x1)[v] - x0[v]  (chunk-4 unrolled gathers) ----
        {
            const int n4 = (min(cnt[v], SLOTS) + 3) & ~3;
            const int* cc = csr_c + v * SLOTS;
            const float* cv = csr_v + v * SLOTS;
            float s[16];
            #pragma unroll
            for (int i = 0; i < 16; ++i) s[i] = 0.f;
            for (int e0 = 0; e0 < n4; e0 += 4) {
                #pragma unroll
                for (int u = 0; u < 4; ++u) {
                    const int c = cc[e0 + u];
                    const float val = cv[e0 + u];
                    u16x8 a0 = *(const u16x8*)(x1b + c * 1024 + jb);
                    u16x8 a1 = *(const u16x8*)(x1b + c * 1024 + jb + 8);
                    #pragma unroll
                    for (int i = 0; i < 8; ++i) {
                        s[i]     = fmaf(val, bf2f(a0[i]), s[i]);
                        s[8 + i] = fmaf(val, bf2f(a1[i]), s[8 + i]);
                    }
                }
            }
            u16x8 z0 = *(const u16x8*)(x0b + v * 1024 + jb);
            u16x8 z1 = *(const u16x8*)(x0b + v * 1024 + jb + 8);
            u16x8 o0, o1;
            #pragma unroll
            for (int i = 0; i < 8; ++i) {
                o0[i] = f2bf(2.f * s[i] - bf2f(z0[i]));
                o1[i] = f2bf(2.f * s[8 + i] - bf2f(z1[i]));
            }
            *(u16x8*)&x2l[wave][jb] = o0;
            *(u16x8*)&x2l[wave][jb + 8] = o1;
        }
        __syncthreads();   // RAW fence for x2l (conservative block barrier)

        // ---- x2 A-fragments from wave-private LDS ----
        #pragma unroll
        for (int mt = 0; mt < 2; ++mt) {
            const int m = mt * 16 + l15;
            const int b = m >> 3, t = m & 7;
            #pragma unroll
            for (int kc = 6; kc < 9; ++kc) {
                const int tw = kc % 3;
                const int tp = t + tw - 1;
                bf16x8 a = {0, 0, 0, 0, 0, 0, 0, 0};
                if ((unsigned)tp < 8u)
                    a = *(const bf16x8*)&x2l[wave][b * 256 + tp * 32 + f0];
                afrag[mt][kc] = a;
            }
        }

        // ---- phase B: MFMA ----
        f32x4 acc[2][4];
        #pragma unroll
        for (int mt = 0; mt < 2; ++mt)
            #pragma unroll
            for (int nt = 0; nt < 4; ++nt)
                acc[mt][nt] = (f32x4){0.f, 0.f, 0.f, 0.f};

        #pragma unroll
        for (int kc = 0; kc < 9; ++kc) {
            #pragma unroll
            for (int nt = 0; nt < 4; ++nt) {
                const int nrow = nt * 16 + l15;
                bf16x8 bfrag = *(const bf16x8*)&wt[nrow * 296 + kc * 32 + f0];
                #pragma unroll
                for (int mt = 0; mt < 2; ++mt)
                    acc[mt][nt] = __builtin_amdgcn_mfma_f32_16x16x32_bf16(
                        afrag[mt][kc], bfrag, acc[mt][nt], 0, 0, 0);
            }
        }

        // ---- epilogue: y store + stats partials (bias cancels under BN) ----
        #pragma unroll
        for (int mt = 0; mt < 2; ++mt)
            #pragma unroll
            for (int nt = 0; nt < 4; ++nt)
                #pragma unroll
                for (int i = 0; i < 4; ++i) {
                    const int m = mt * 16 + lhi * 4 + i;
                    const int b = m >> 3, t = m & 7;
                    const int col = nt * 16 + l15;
                    const float val = acc[mt][nt][i];
                    ssum[nt] += val;
                    ssq[nt]  += val * val;
                    const int idx = ((b * V + v) * 8 + t) * 64 + col;
                    if (YBF) yb[idx] = f2bf(val);
                    else     yf[idx] = val;
                }
        // WAR on x2l vs next iteration's writes: same-wave DS ops are in-order.
    }

    #pragma unroll
    for (int nt = 0; nt < 4; ++nt) {
        const int col = nt * 16 + l15;
        atomicAdd(&sstat[col], ssum[nt]);
        atomicAdd(&sstat[64 + col], ssq[nt]);
    }
    __syncthreads();
    if (threadIdx.x < 128) atomicAdd(&stats[threadIdx.x], sstat[threadIdx.x]);
}

// ---------------- fold mean/var/gamma/beta -> scale/shift ----------------
__global__ __launch_bounds__(64)
void finalize_kernel(const float* __restrict__ gamma, const float* __restrict__ beta,
                     float* __restrict__ stats) {
    int o = threadIdx.x;
    float n = (float)(B * V * T);
    float mean = stats[o] / n;
    float var = stats[64 + o] / n - mean * mean;
    float sc = gamma[o] * rsqrtf(var + EPS);
    stats[128 + o] = sc;
    stats[192 + o] = beta[o] - mean * sc;
}

// ---------------- normalize + ReLU ----------------
template<int YBF>
__global__ __launch_bounds__(256)
void norm_kernel(const unsigned short* __restrict__ yb, float* __restrict__ out,
                 const float* __restrict__ stats) {
    const int total = B * V * T * 64;
    if (YBF) {
        const int start = (blockIdx.x * 256 + threadIdx.x) * 8;
        const int ob = start & 63;
        float sc[8], sh[8];
        #pragma unroll
        for (int c = 0; c < 8; ++c) { sc[c] = stats[128 + ob + c]; sh[c] = stats[192 + ob + c]; }
        for (int i0 = start; i0 < total; i0 += gridDim.x * 256 * 8) {
            u16x8 yv = *(const u16x8*)(yb + i0);
            float4v r0, r1;
            #pragma unroll
            for (int c = 0; c < 8; ++c) {
                float val = fmaxf(bf2f(yv[c]) * sc[c] + sh[c], 0.f);
                if (c < 4) r0[c] = val; else r1[c - 4] = val;
            }
            *(float4v*)(out + i0) = r0;
            *(float4v*)(out + i0 + 4) = r1;
        }
    } else {
        const int start = (blockIdx.x * 256 + threadIdx.x) * 4;
        const int ob = start & 63;
        float sc[4], sh[4];
        #pragma unroll
        for (int c = 0; c < 4; ++c) { sc[c] = stats[128 + ob + c]; sh[c] = stats[192 + ob + c]; }
        for (int i0 = start; i0 < total; i0 += gridDim.x * 256 * 4) {
            float4v v4 = *(float4v*)(out + i0);
            #pragma unroll
            for (int c = 0; c < 4; ++c)
                v4[c] = fmaxf(v4[c] * sc[c] + sh[c], 0.f);
            *(float4v*)(out + i0) = v4;
        }
    }
}

extern "C" void kernel_launch(void* const* d_in, const int* in_sizes, int n_in,
                              void* d_out, int out_size, void* d_ws, size_t ws_size,
                              hipStream_t stream) {
    const float* x        = (const float*)d_in[0];
    const float* lap_vals = (const float*)d_in[1];
    const float* W        = (const float*)d_in[2];
    // d_in[3] = bias: cancels exactly under training-mode BN
    const float* gamma    = (const float*)d_in[4];
    const float* beta     = (const float*)d_in[5];
    const int*   rows     = (const int*)d_in[6];
    const int*   cols     = (const int*)d_in[7];
    float* out = (float*)d_out;
    char*  ws  = (char*)d_ws;

    float*          stats = (float*)(ws + STATS_OFF);
    int*            cnt   = (int*)(ws + CNT_OFF);
    int*            csr_c = (int*)(ws + CSRC_OFF);
    float*          csr_v = (float*)(ws + CSRV_OFF);
    unsigned short* x0b   = (unsigned short*)(ws + X0B_OFF);
    unsigned short* x1b   = (unsigned short*)(ws + X1B_OFF);
    unsigned short* ybp   = (unsigned short*)(ws + YB_OFF);

    const bool ybf = (ws_size >= (size_t)WS_NEED_YB);

    // zero stats + cnt + csr arrays (csr zero-fill makes padded slots inert)
    hipMemsetAsync(ws + STATS_OFF, 0, (size_t)X0B_OFF, stream);

    convert_kernel<<<24576, 256, 0, stream>>>(x, x0b);
    scatter_kernel<<<(NNZ + 255) / 256, 256, 0, stream>>>(rows, cols, lap_vals, cnt, csr_c, csr_v);
    spmm1_kernel<<<V, 256, 0, stream>>>(x0b, cnt, csr_c, csr_v, x1b);
    if (ybf) dense_kernel<1><<<V / 64, 256, 0, stream>>>(x0b, x1b, cnt, csr_c, csr_v, W, stats, ybp, nullptr);
    else     dense_kernel<0><<<V / 64, 256, 0, stream>>>(x0b, x1b, cnt, csr_c, csr_v, W, stats, nullptr, out);
    finalize_kernel<<<1, 64, 0, stream>>>(gamma, beta, stats);
    if (ybf) norm_kernel<1><<<4096, 256, 0, stream>>>(ybp, out, stats);
    else     norm_kernel<0><<<4096, 256, 0, stream>>>(nullptr, out, stats);
}

// Round 8
// 570.368 us; speedup vs baseline: 1.5155x; 1.0203x over previous
//
#include <hip/hip_runtime.h>

#define V 49152
#define B 4
#define T 8
#define NNZ (9 * V)
#define EPS 1e-5f
#define SLOTS 32

typedef __attribute__((ext_vector_type(8))) short bf16x8;
typedef __attribute__((ext_vector_type(4))) float f32x4;
typedef __attribute__((ext_vector_type(4))) float float4v;
typedef __attribute__((ext_vector_type(8))) unsigned short u16x8;
typedef __attribute__((ext_vector_type(4))) unsigned short u16x4;

// ---------------- ws layout (bytes) ----------------
#define STATS_OFF 0LL          // 256 floats: sum[64]|sumsq[64]|scale[64]|shift[64]
#define CNT_OFF   1024LL       // V ints
#define CSRC_OFF  197632LL     // V*SLOTS ints
#define CSRV_OFF  6489088LL    // V*SLOTS floats
#define X0B_OFF   12780544LL   // V*1024 bf16   (memset zeroes [0, X0B_OFF))
#define X1B_OFF   113443840LL  // V*1024 bf16
#define YB_OFF    214107136LL  // B*V*T*64 bf16 (only if ws is big enough)
#define WS_NEED_YB 415433728LL

__device__ inline unsigned short f2bf(float f) {
    unsigned u = __builtin_bit_cast(unsigned, f);
    u += 0x7fffu + ((u >> 16) & 1u);
    return (unsigned short)(u >> 16);
}
__device__ inline float bf2f(unsigned short h) {
    return __builtin_bit_cast(float, ((unsigned)h) << 16);
}

// ---------------- convert x fp32 [B][V][T*F] -> bf16 [V][B][T*F] ----------------
__global__ __launch_bounds__(256)
void convert_kernel(const float* __restrict__ x, unsigned short* __restrict__ x0b) {
    unsigned gid = blockIdx.x * 256 + threadIdx.x;   // V*128 threads total
    unsigned v = gid >> 7;
    unsigned s = gid & 127;              // 8-short chunk within the 1024-short row
    unsigned b = s >> 5;                 // s*8 / 256
    unsigned j = (s * 8) & 255;
    const float4v* src = (const float4v*)(x + (size_t)(b * V + v) * 256 + j);
    float4v f0 = src[0], f1 = src[1];
    u16x8 o;
    o[0] = f2bf(f0[0]); o[1] = f2bf(f0[1]); o[2] = f2bf(f0[2]); o[3] = f2bf(f0[3]);
    o[4] = f2bf(f1[0]); o[5] = f2bf(f1[1]); o[6] = f2bf(f1[2]); o[7] = f2bf(f1[3]);
    *(u16x8*)(x0b + v * 1024 + s * 8) = o;
}

// ---------------- padded-CSR build (pad slots stay 0 from memset) ----------------
__global__ __launch_bounds__(256)
void scatter_kernel(const int* __restrict__ rows, const int* __restrict__ cols,
                    const float* __restrict__ vals, int* __restrict__ cnt,
                    int* __restrict__ csr_c, float* __restrict__ csr_v) {
    int e = blockIdx.x * 256 + threadIdx.x;
    if (e >= NNZ) return;
    int r = rows[e];
    int slot = atomicAdd(&cnt[r], 1);
    if (slot < SLOTS) {
        csr_c[r * SLOTS + slot] = cols[e];
        csr_v[r * SLOTS + slot] = vals[e];
    }
}

// ---------------- SpMM 1: x1 = L @ x0 ----------------
// Lanes 0-31 preload the row's CSR entries; __shfl broadcasts them so the
// data gathers have no dependent uniform-load stage on the critical path.
__global__ __launch_bounds__(256)
void spmm1_kernel(const unsigned short* __restrict__ x0b, const int* __restrict__ cnt,
                  const int* __restrict__ csr_c, const float* __restrict__ csr_v,
                  unsigned short* __restrict__ x1b) {
    int r = blockIdx.x;
    int j = threadIdx.x * 4;
    int lane = threadIdx.x & 63;
    int n8 = (min(cnt[r], SLOTS) + 7) & ~7;
    int   ccr = 0;
    float cvr = 0.f;
    if (lane < 32) {                       // pads beyond n are 0 from memset
        ccr = csr_c[r * SLOTS + lane];
        cvr = csr_v[r * SLOTS + lane];
    }
    float s0 = 0.f, s1 = 0.f, s2 = 0.f, s3 = 0.f;
    for (int e0 = 0; e0 < n8; e0 += 8) {
        #pragma unroll
        for (int u = 0; u < 8; ++u) {
            int   c   = __shfl(ccr, e0 + u);   // pad: c=0,val=0 -> contributes 0
            float val = __shfl(cvr, e0 + u);
            u16x4 xv = *(const u16x4*)(x0b + c * 1024 + j);
            s0 = fmaf(val, bf2f(xv[0]), s0);
            s1 = fmaf(val, bf2f(xv[1]), s1);
            s2 = fmaf(val, bf2f(xv[2]), s2);
            s3 = fmaf(val, bf2f(xv[3]), s3);
        }
    }
    u16x4 o;
    o[0] = f2bf(s0); o[1] = f2bf(s1); o[2] = f2bf(s2); o[3] = f2bf(s3);
    *(u16x4*)(x1b + r * 1024 + j) = o;
}

// ---------------- fused: spmm2 (x2 per v, wave-private LDS) + dense MFMA + BN stats ----------------
// 64 v per block, 4 waves. CSR entries for v are shfl-broadcast from lanes 0-31;
// next vi's entries prefetched before the barrier (hidden under MFMA phase).
template<int YBF>
__global__ __launch_bounds__(256, 3)
void dense_kernel(const unsigned short* __restrict__ x0b, const unsigned short* __restrict__ x1b,
                  const int* __restrict__ cnt, const int* __restrict__ csr_c,
                  const float* __restrict__ csr_v, const float* __restrict__ W,
                  float* __restrict__ stats, unsigned short* __restrict__ yb,
                  float* __restrict__ yf) {
    __shared__ short wt[64 * 296];     // W^T: wt[o][k]; dword-stride 148 -> <=2-way = free
    __shared__ short x2l[4][1024];     // per-wave x2[v] slice (wave-private)
    __shared__ float sstat[128];

    for (int idx = threadIdx.x; idx < 288 * 64; idx += 256) {
        int k = idx >> 6, o = idx & 63;
        wt[o * 296 + k] = (short)f2bf(W[idx]);
    }
    if (threadIdx.x < 128) sstat[threadIdx.x] = 0.f;
    __syncthreads();

    const int wave = threadIdx.x >> 6;
    const int lane = threadIdx.x & 63;
    const int l15 = lane & 15, lhi = lane >> 4;
    const int f0 = lhi * 8;
    const int jb = lane * 16;

    float ssum[4] = {0.f, 0.f, 0.f, 0.f};
    float ssq[4]  = {0.f, 0.f, 0.f, 0.f};

    // prologue: CSR entries + degree for vi=0
    int   ccr = 0, ncur = 0;
    float cvr = 0.f;
    {
        const int v0 = blockIdx.x * 64 + wave;
        if (lane < 32) {
            ccr = csr_c[v0 * SLOTS + lane];
            cvr = csr_v[v0 * SLOTS + lane];
        }
        ncur = cnt[v0];
    }

    for (int vi = 0; vi < 16; ++vi) {
        const int v = blockIdx.x * 64 + vi * 4 + wave;

        // ---- issue x0/x1 A-fragment loads early (independent of the gather) ----
        bf16x8 afrag[2][9];
        #pragma unroll
        for (int mt = 0; mt < 2; ++mt) {
            const int m = mt * 16 + l15;
            const int b = m >> 3, t = m & 7;
            #pragma unroll
            for (int kc = 0; kc < 6; ++kc) {
                const int kk = kc / 3, tw = kc % 3;
                const int tp = t + tw - 1;
                bf16x8 a = {0, 0, 0, 0, 0, 0, 0, 0};
                if ((unsigned)tp < 8u) {
                    const unsigned short* src = (kk == 0) ? x0b : x1b;
                    a = *(const bf16x8*)(src + v * 1024 + b * 256 + tp * 32 + f0);
                }
                afrag[mt][kc] = a;
            }
        }

        // ---- phase A: x2[v] = 2*(L@x1)[v] - x0[v]; shfl-broadcast CSR entries ----
        {
            const int n4 = (min(ncur, SLOTS) + 3) & ~3;
            // -x0 term loads issued before the gather loop (independent)
            u16x8 z0 = *(const u16x8*)(x0b + v * 1024 + jb);
            u16x8 z1 = *(const u16x8*)(x0b + v * 1024 + jb + 8);
            float s[16];
            #pragma unroll
            for (int i = 0; i < 16; ++i) s[i] = 0.f;
            for (int e0 = 0; e0 < n4; e0 += 4) {
                #pragma unroll
                for (int u = 0; u < 4; ++u) {
                    const int   c   = __shfl(ccr, e0 + u);   // pad lanes hold 0/0
                    const float val = __shfl(cvr, e0 + u);
                    u16x8 a0 = *(const u16x8*)(x1b + c * 1024 + jb);
                    u16x8 a1 = *(const u16x8*)(x1b + c * 1024 + jb + 8);
                    #pragma unroll
                    for (int i = 0; i < 8; ++i) {
                        s[i]     = fmaf(val, bf2f(a0[i]), s[i]);
                        s[8 + i] = fmaf(val, bf2f(a1[i]), s[8 + i]);
                    }
                }
            }
            u16x8 o0, o1;
            #pragma unroll
            for (int i = 0; i < 8; ++i) {
                o0[i] = f2bf(2.f * s[i] - bf2f(z0[i]));
                o1[i] = f2bf(2.f * s[8 + i] - bf2f(z1[i]));
            }
            *(u16x8*)&x2l[wave][jb] = o0;
            *(u16x8*)&x2l[wave][jb + 8] = o1;
        }

        // ---- prefetch next vi's CSR entries (hides under barrier + MFMA) ----
        int   ccn = 0, ncn = 0;
        float cvn = 0.f;
        if (vi < 15) {
            const int vn = v + 4;
            if (lane < 32) {
                ccn = csr_c[vn * SLOTS + lane];
                cvn = csr_v[vn * SLOTS + lane];
            }
            ncn = cnt[vn];
        }

        __syncthreads();   // RAW fence for x2l (conservative block barrier)

        // ---- x2 A-fragments from wave-private LDS ----
        #pragma unroll
        for (int mt = 0; mt < 2; ++mt) {
            const int m = mt * 16 + l15;
            const int b = m >> 3, t = m & 7;
            #pragma unroll
            for (int kc = 6; kc < 9; ++kc) {
                const int tw = kc % 3;
                const int tp = t + tw - 1;
                bf16x8 a = {0, 0, 0, 0, 0, 0, 0, 0};
                if ((unsigned)tp < 8u)
                    a = *(const bf16x8*)&x2l[wave][b * 256 + tp * 32 + f0];
                afrag[mt][kc] = a;
            }
        }

        // ---- phase B: MFMA ----
        f32x4 acc[2][4];
        #pragma unroll
        for (int mt = 0; mt < 2; ++mt)
            #pragma unroll
            for (int nt = 0; nt < 4; ++nt)
                acc[mt][nt] = (f32x4){0.f, 0.f, 0.f, 0.f};

        #pragma unroll
        for (int kc = 0; kc < 9; ++kc) {
            #pragma unroll
            for (int nt = 0; nt < 4; ++nt) {
                const int nrow = nt * 16 + l15;
                bf16x8 bfrag = *(const bf16x8*)&wt[nrow * 296 + kc * 32 + f0];
                #pragma unroll
                for (int mt = 0; mt < 2; ++mt)
                    acc[mt][nt] = __builtin_amdgcn_mfma_f32_16x16x32_bf16(
                        afrag[mt][kc], bfrag, acc[mt][nt], 0, 0, 0);
            }
        }

        // ---- epilogue: y store + stats partials (bias cancels under BN) ----
        #pragma unroll
        for (int mt = 0; mt < 2; ++mt)
            #pragma unroll
            for (int nt = 0; nt < 4; ++nt)
                #pragma unroll
                for (int i = 0; i < 4; ++i) {
                    const int m = mt * 16 + lhi * 4 + i;
                    const int b = m >> 3, t = m & 7;
                    const int col = nt * 16 + l15;
                    const float val = acc[mt][nt][i];
                    ssum[nt] += val;
                    ssq[nt]  += val * val;
                    const int idx = ((b * V + v) * 8 + t) * 64 + col;
                    if (YBF) yb[idx] = f2bf(val);
                    else     yf[idx] = val;
                }
        // WAR on x2l vs next iteration's writes: same-wave DS ops are in-order.
        ccr = ccn; cvr = cvn; ncur = ncn;
    }

    #pragma unroll
    for (int nt = 0; nt < 4; ++nt) {
        const int col = nt * 16 + l15;
        atomicAdd(&sstat[col], ssum[nt]);
        atomicAdd(&sstat[64 + col], ssq[nt]);
    }
    __syncthreads();
    if (threadIdx.x < 128) atomicAdd(&stats[threadIdx.x], sstat[threadIdx.x]);
}

// ---------------- fold mean/var/gamma/beta -> scale/shift ----------------
__global__ __launch_bounds__(64)
void finalize_kernel(const float* __restrict__ gamma, const float* __restrict__ beta,
                     float* __restrict__ stats) {
    int o = threadIdx.x;
    float n = (float)(B * V * T);
    float mean = stats[o] / n;
    float var = stats[64 + o] / n - mean * mean;
    float sc = gamma[o] * rsqrtf(var + EPS);
    stats[128 + o] = sc;
    stats[192 + o] = beta[o] - mean * sc;
}

// ---------------- normalize + ReLU ----------------
template<int YBF>
__global__ __launch_bounds__(256)
void norm_kernel(const unsigned short* __restrict__ yb, float* __restrict__ out,
                 const float* __restrict__ stats) {
    const int total = B * V * T * 64;
    if (YBF) {
        const int start = (blockIdx.x * 256 + threadIdx.x) * 8;
        const int ob = start & 63;
        float sc[8], sh[8];
        #pragma unroll
        for (int c = 0; c < 8; ++c) { sc[c] = stats[128 + ob + c]; sh[c] = stats[192 + ob + c]; }
        for (int i0 = start; i0 < total; i0 += gridDim.x * 256 * 8) {
            u16x8 yv = *(const u16x8*)(yb + i0);
            float4v r0, r1;
            #pragma unroll
            for (int c = 0; c < 8; ++c) {
                float val = fmaxf(bf2f(yv[c]) * sc[c] + sh[c], 0.f);
                if (c < 4) r0[c] = val; else r1[c - 4] = val;
            }
            *(float4v*)(out + i0) = r0;
            *(float4v*)(out + i0 + 4) = r1;
        }
    } else {
        const int start = (blockIdx.x * 256 + threadIdx.x) * 4;
        const int ob = start & 63;
        float sc[4], sh[4];
        #pragma unroll
        for (int c = 0; c < 4; ++c) { sc[c] = stats[128 + ob + c]; sh[c] = stats[192 + ob + c]; }
        for (int i0 = start; i0 < total; i0 += gridDim.x * 256 * 4) {
            float4v v4 = *(float4v*)(out + i0);
            #pragma unroll
            for (int c = 0; c < 4; ++c)
                v4[c] = fmaxf(v4[c] * sc[c] + sh[c], 0.f);
            *(float4v*)(out + i0) = v4;
        }
    }
}

extern "C" void kernel_launch(void* const* d_in, const int* in_sizes, int n_in,
                              void* d_out, int out_size, void* d_ws, size_t ws_size,
                              hipStream_t stream) {
    const float* x        = (const float*)d_in[0];
    const float* lap_vals = (const float*)d_in[1];
    const float* W        = (const float*)d_in[2];
    // d_in[3] = bias: cancels exactly under training-mode BN
    const float* gamma    = (const float*)d_in[4];
    const float* beta     = (const float*)d_in[5];
    const int*   rows     = (const int*)d_in[6];
    const int*   cols     = (const int*)d_in[7];
    float* out = (float*)d_out;
    char*  ws  = (char*)d_ws;

    float*          stats = (float*)(ws + STATS_OFF);
    int*            cnt   = (int*)(ws + CNT_OFF);
    int*            csr_c = (int*)(ws + CSRC_OFF);
    float*          csr_v = (float*)(ws + CSRV_OFF);
    unsigned short* x0b   = (unsigned short*)(ws + X0B_OFF);
    unsigned short* x1b   = (unsigned short*)(ws + X1B_OFF);
    unsigned short* ybp   = (unsigned short*)(ws + YB_OFF);

    const bool ybf = (ws_size >= (size_t)WS_NEED_YB);

    // zero stats + cnt + csr arrays (csr zero-fill makes padded slots inert)
    hipMemsetAsync(ws + STATS_OFF, 0, (size_t)X0B_OFF, stream);

    convert_kernel<<<24576, 256, 0, stream>>>(x, x0b);
    scatter_kernel<<<(NNZ + 255) / 256, 256, 0, stream>>>(rows, cols, lap_vals, cnt, csr_c, csr_v);
    spmm1_kernel<<<V, 256, 0, stream>>>(x0b, cnt, csr_c, csr_v, x1b);
    if (ybf) dense_kernel<1><<<V / 64, 256, 0, stream>>>(x0b, x1b, cnt, csr_c, csr_v, W, stats, ybp, nullptr);
    else     dense_kernel<0><<<V / 64, 256, 0, stream>>>(x0b, x1b, cnt, csr_c, csr_v, W, stats, nullptr, out);
    finalize_kernel<<<1, 64, 0, stream>>>(gamma, beta, stats);
    if (ybf) norm_kernel<1><<<4096, 256, 0, stream>>>(ybp, out, stats);
    else     norm_kernel<0><<<4096, 256, 0, stream>>>(nullptr, out, stats);
}